// Round 1
// baseline (929.326 us; speedup 1.0000x reference)
//
#include <hip/hip_runtime.h>
#include <math.h>

#define KK 512
#define VV 50257
#define VP 50272   // padded mhq row stride (halfs)
#define DD 768
#define RR 192

#define LAM 0.3f
#define GAM 0.3f
#define L2E 1.44269504088896340736f
#define ENC_NEG_INF 0x007FFFFFu

typedef __bf16 bf16x8 __attribute__((ext_vector_type(8)));
typedef _Float16 f16x8 __attribute__((ext_vector_type(8)));
typedef _Float16 f16x2 __attribute__((ext_vector_type(2)));
typedef unsigned short u16x8 __attribute__((ext_vector_type(8)));
typedef float f32x4 __attribute__((ext_vector_type(4)));

// ---------------------------------------------------------------------------
// helpers
// ---------------------------------------------------------------------------
static __device__ __forceinline__ float get_eps(const float* p_log_eps) {
  return log1pf(expf(p_log_eps[0])) + 0.001f;  // softplus(log_eps)+1e-3
}

static __device__ __forceinline__ float fast_exp2(float x) {
  return __builtin_amdgcn_exp2f(x);  // v_exp_f32 (2^x)
}

// order-preserving float<->unsigned encode for atomicMax
static __device__ __forceinline__ unsigned enc_f(float f) {
  unsigned u = __builtin_bit_cast(unsigned, f);
  return (u & 0x80000000u) ? ~u : (u | 0x80000000u);
}
static __device__ __forceinline__ float dec_f(unsigned e) {
  unsigned u = (e & 0x80000000u) ? (e ^ 0x80000000u) : ~e;
  return __builtin_bit_cast(float, u);
}

// fp32 -> bf16 rne (for the non-eye fallback GEMM only)
static __device__ __forceinline__ unsigned short f2bf(float x) {
  unsigned u = __builtin_bit_cast(unsigned, x);
  u += 0x7fffu + ((u >> 16) & 1u);
  return (unsigned short)(u >> 16);
}
static __device__ __forceinline__ float bf2f(unsigned short h) {
  unsigned u = ((unsigned)h) << 16;
  return __builtin_bit_cast(float, u);
}

// ---------------------------------------------------------------------------
// prep: fused small-kernel pass.
//  blocks [0,576):    Ut16[r,d] = fp16(U[d,r])
//  blocks [576,773):  lv2 = 0 (50264 incl pad)
//  block 773:         slots init (Mv/Mu maxima, eye flag)
//  blocks [774,1286): a16 = fp16(normalize(anchors)), one block per row
// slots: [0..11]=Mv2, [12..23]=Mu2, [24]=eye_flag
// ---------------------------------------------------------------------------
__global__ __launch_bounds__(256)
void prep(const float* __restrict__ U, float* __restrict__ lv2,
          unsigned* __restrict__ slots, const float* __restrict__ anchors,
          _Float16* __restrict__ Ut16, _Float16* __restrict__ a16) {
  int bid = blockIdx.x;
  int t = threadIdx.x;
  if (bid < 576) {
    int idx = bid * 256 + t;
    int r = idx / DD;
    int d = idx - r * DD;
    Ut16[idx] = (_Float16)U[(size_t)d * RR + r];
  } else if (bid < 773) {
    int i = (bid - 576) * 256 + t;
    if (i < 50264) lv2[i] = 0.f;
  } else if (bid == 773) {
    if (t < 24) slots[t] = (t == 0) ? 0x80000000u : ENC_NEG_INF;  // enc(0), enc(-inf)
    if (t == 24) slots[24] = 1u;                                  // eye_flag
  } else {
    int r = bid - 774;
    const float* x = anchors + (size_t)r * DD;
    float v0 = x[t], v1 = x[t + 256], v2 = x[t + 512];
    __shared__ float red[256];
    red[t] = v0 * v0 + v1 * v1 + v2 * v2;
    __syncthreads();
    for (int off = 128; off > 0; off >>= 1) {
      if (t < off) red[t] += red[t + off];
      __syncthreads();
    }
    float inv = 1.0f / fmaxf(sqrtf(red[0]), 1e-12f);
    _Float16* y = a16 + (size_t)r * DD;
    y[t] = (_Float16)(v0 * inv);
    y[t + 256] = (_Float16)(v1 * inv);
    y[t + 512] = (_Float16)(v2 * inv);
  }
}

// ---------------------------------------------------------------------------
// check Wp == I (exact); clears eye flag on mismatch
// ---------------------------------------------------------------------------
__global__ __launch_bounds__(256)
void check_eye(const float* __restrict__ Wp, unsigned* __restrict__ flag) {
  int i = blockIdx.x * 256 + threadIdx.x;
  if (i >= DD * DD) return;
  int r = i / DD;
  int c = i - r * DD;
  float expect = (r == c) ? 1.f : 0.f;
  if (Wp[i] != expect) atomicAnd(flag, 0u);
}

// ---------------------------------------------------------------------------
// FALLBACK ONLY (Wp != I): split-bf16 3-term GEMM w_raw = WE @ Wp^T -> fp16.
// When *eyeflag, returns immediately (norm_w reads WE directly).
// ---------------------------------------------------------------------------
#define BM 128
#define BN 128
#define BK 32
#define LDKB 40  // bf16 fallback LDS stride
#define LDK 40   // fp16 LDS stride (pad -> 2-way banks, free)

__global__ __launch_bounds__(256, 2)
void gemm_we_fallback(const float* __restrict__ A, const float* __restrict__ B,
                      _Float16* __restrict__ C, int M, int N, int Kd,
                      const unsigned* __restrict__ eyeflag) {
  if (*eyeflag) return;
  __shared__ unsigned short As[2][BM][LDKB];
  __shared__ unsigned short Bs[2][BN][LDKB];
  const int tid = threadIdx.x;
  const int bm = blockIdx.y * BM;
  const int bn = blockIdx.x * BN;
  const int srow = tid >> 1;
  const int skb = (tid & 1) << 4;
  const int wave = tid >> 6;
  const int lane = tid & 63;
  const int wm = (wave >> 1) << 6;
  const int wn = (wave & 1) << 6;
  const int lm = lane & 15;
  const int quad = lane >> 4;
  f32x4 acc[4][4];
#pragma unroll
  for (int i = 0; i < 4; ++i)
#pragma unroll
    for (int j = 0; j < 4; ++j) acc[i][j] = (f32x4){0.f, 0.f, 0.f, 0.f};
  const int ra = bm + srow;
  const int rb = bn + srow;
  for (int k0 = 0; k0 < Kd; k0 += BK) {
    float va[16], vb[16];
    if (ra < M) {
      const float4* p = (const float4*)(A + (size_t)ra * Kd + k0 + skb);
      ((float4*)va)[0] = p[0]; ((float4*)va)[1] = p[1];
      ((float4*)va)[2] = p[2]; ((float4*)va)[3] = p[3];
    } else {
#pragma unroll
      for (int q = 0; q < 16; ++q) va[q] = 0.f;
    }
    if (rb < N) {
      const float4* p = (const float4*)(B + (size_t)rb * Kd + k0 + skb);
      ((float4*)vb)[0] = p[0]; ((float4*)vb)[1] = p[1];
      ((float4*)vb)[2] = p[2]; ((float4*)vb)[3] = p[3];
    } else {
#pragma unroll
      for (int q = 0; q < 16; ++q) vb[q] = 0.f;
    }
    __syncthreads();
    {
      u16x8 h0, h1, l0, l1;
#pragma unroll
      for (int q = 0; q < 8; ++q) {
        unsigned short h = f2bf(va[q]);
        h0[q] = h; l0[q] = f2bf(va[q] - bf2f(h));
        h = f2bf(va[q + 8]);
        h1[q] = h; l1[q] = f2bf(va[q + 8] - bf2f(h));
      }
      *(u16x8*)&As[0][srow][skb] = h0; *(u16x8*)&As[0][srow][skb + 8] = h1;
      *(u16x8*)&As[1][srow][skb] = l0; *(u16x8*)&As[1][srow][skb + 8] = l1;
#pragma unroll
      for (int q = 0; q < 8; ++q) {
        unsigned short h = f2bf(vb[q]);
        h0[q] = h; l0[q] = f2bf(vb[q] - bf2f(h));
        h = f2bf(vb[q + 8]);
        h1[q] = h; l1[q] = f2bf(vb[q + 8] - bf2f(h));
      }
      *(u16x8*)&Bs[0][srow][skb] = h0; *(u16x8*)&Bs[0][srow][skb + 8] = h1;
      *(u16x8*)&Bs[1][srow][skb] = l0; *(u16x8*)&Bs[1][srow][skb + 8] = l1;
    }
    __syncthreads();
    bf16x8 Ah[4], Al[4], Bh[4], Bl[4];
#pragma unroll
    for (int i = 0; i < 4; ++i) {
      Ah[i] = *(const bf16x8*)&As[0][wm + i * 16 + lm][quad * 8];
      Al[i] = *(const bf16x8*)&As[1][wm + i * 16 + lm][quad * 8];
      Bh[i] = *(const bf16x8*)&Bs[0][wn + i * 16 + lm][quad * 8];
      Bl[i] = *(const bf16x8*)&Bs[1][wn + i * 16 + lm][quad * 8];
    }
#pragma unroll
    for (int i = 0; i < 4; ++i)
#pragma unroll
      for (int j = 0; j < 4; ++j) {
        acc[i][j] = __builtin_amdgcn_mfma_f32_16x16x32_bf16(Ah[i], Bh[j], acc[i][j], 0, 0, 0);
        acc[i][j] = __builtin_amdgcn_mfma_f32_16x16x32_bf16(Ah[i], Bl[j], acc[i][j], 0, 0, 0);
        acc[i][j] = __builtin_amdgcn_mfma_f32_16x16x32_bf16(Al[i], Bh[j], acc[i][j], 0, 0, 0);
      }
  }
#pragma unroll
  for (int i = 0; i < 4; ++i)
#pragma unroll
    for (int j = 0; j < 4; ++j) {
      int col = bn + wn + j * 16 + lm;
#pragma unroll
      for (int r = 0; r < 4; ++r) {
        int row = bm + wm + i * 16 + quad * 4 + r;
        if (row < M && col < N) C[(size_t)row * N + col] = (_Float16)acc[i][j][r];
      }
    }
}

// ---------------------------------------------------------------------------
// norm_w: w16[r,:] = fp16(normalize(src[r,:])), src = eye ? WE(f32) : w16(f16)
// ---------------------------------------------------------------------------
__global__ __launch_bounds__(256)
void norm_w(const float* __restrict__ WE, _Float16* __restrict__ w16,
            const unsigned* __restrict__ eyeflag) {
  int r = blockIdx.x;
  int t = threadIdx.x;
  float v0, v1, v2;
  if (*eyeflag) {
    const float* x = WE + (size_t)r * DD;
    v0 = x[t]; v1 = x[t + 256]; v2 = x[t + 512];
  } else {
    const _Float16* x = w16 + (size_t)r * DD;
    v0 = (float)x[t]; v1 = (float)x[t + 256]; v2 = (float)x[t + 512];
  }
  __shared__ float red[256];
  red[t] = v0 * v0 + v1 * v1 + v2 * v2;
  __syncthreads();
  for (int off = 128; off > 0; off >>= 1) {
    if (t < off) red[t] += red[t + off];
    __syncthreads();
  }
  float inv = 1.0f / fmaxf(sqrtf(red[0]), 1e-12f);
  _Float16* y = w16 + (size_t)r * DD;
  y[t] = (_Float16)(v0 * inv);
  y[t + 256] = (_Float16)(v1 * inv);
  y[t + 512] = (_Float16)(v2 * inv);
}

// ---------------------------------------------------------------------------
// fp16 single-term MFMA GEMM: C[M,N] = A[M,Kd]*B[N,Kd]^T. 128x128 tile, BK=32,
// 4 waves x 4x4 frags of mfma_f32_16x16x32_f16. F16OUT: fp16 or fp32 C.
// ---------------------------------------------------------------------------
template <int F16OUT>
__global__ __launch_bounds__(256, 2)
void gemm16(const _Float16* __restrict__ A, const _Float16* __restrict__ B,
            void* __restrict__ Cv, int M, int N, int Kd) {
  __shared__ _Float16 As[BM][LDK];
  __shared__ _Float16 Bs[BN][LDK];
  const int tid = threadIdx.x;
  const int bm = blockIdx.y * BM;
  const int bn = blockIdx.x * BN;
  const int srow = tid >> 1;
  const int skb = (tid & 1) << 4;
  const int wave = tid >> 6;
  const int lane = tid & 63;
  const int wm = (wave >> 1) << 6;
  const int wn = (wave & 1) << 6;
  const int lm = lane & 15;
  const int quad = lane >> 4;
  f32x4 acc[4][4];
#pragma unroll
  for (int i = 0; i < 4; ++i)
#pragma unroll
    for (int j = 0; j < 4; ++j) acc[i][j] = (f32x4){0.f, 0.f, 0.f, 0.f};
  const int ra = bm + srow;
  const int rb = bn + srow;
  for (int k0 = 0; k0 < Kd; k0 += BK) {
    f16x8 a0 = (f16x8)(_Float16)0, a1 = a0, b0 = a0, b1 = a0;
    if (ra < M) {
      const f16x8* p = (const f16x8*)(A + (size_t)ra * Kd + k0 + skb);
      a0 = p[0]; a1 = p[1];
    }
    if (rb < N) {
      const f16x8* p = (const f16x8*)(B + (size_t)rb * Kd + k0 + skb);
      b0 = p[0]; b1 = p[1];
    }
    __syncthreads();
    *(f16x8*)&As[srow][skb] = a0; *(f16x8*)&As[srow][skb + 8] = a1;
    *(f16x8*)&Bs[srow][skb] = b0; *(f16x8*)&Bs[srow][skb + 8] = b1;
    __syncthreads();
    f16x8 Af[4], Bf[4];
#pragma unroll
    for (int i = 0; i < 4; ++i) {
      Af[i] = *(const f16x8*)&As[wm + i * 16 + lm][quad * 8];
      Bf[i] = *(const f16x8*)&Bs[wn + i * 16 + lm][quad * 8];
    }
#pragma unroll
    for (int i = 0; i < 4; ++i)
#pragma unroll
      for (int j = 0; j < 4; ++j)
        acc[i][j] = __builtin_amdgcn_mfma_f32_16x16x32_f16(Af[i], Bf[j], acc[i][j], 0, 0, 0);
  }
#pragma unroll
  for (int i = 0; i < 4; ++i)
#pragma unroll
    for (int j = 0; j < 4; ++j) {
      int col = bn + wn + j * 16 + lm;
#pragma unroll
      for (int r = 0; r < 4; ++r) {
        int row = bm + wm + i * 16 + quad * 4 + r;
        if (row < M && col < N) {
          if (F16OUT)
            ((_Float16*)Cv)[(size_t)row * N + col] = (_Float16)acc[i][j][r];
          else
            ((float*)Cv)[(size_t)row * N + col] = acc[i][j][r];
        }
      }
    }
}

// ---------------------------------------------------------------------------
// FUSED S+P GEMM (roomy-workspace path; requires mhq NOT aliasing w16):
//   accP = aU16 @ wU16^T (Kd=RR), accS = a16 @ w16^T (Kd=DD), then epilogue
//   Sd <- scale*S + bias ;  mhq <- fp16( relu(AA+BB-2(S+P)) * L2E/eps )
// Removes the 103 MB f32 S store + 103 MB reload of the two-kernel path.
// Math identical: S went through f32 memory before (exact), now stays in acc.
// ~200 VGPR (two 4x4xf32x4 acc sets) still fits __launch_bounds__(256,2).
// ---------------------------------------------------------------------------
__global__ __launch_bounds__(256, 2)
void gemm_sp(const _Float16* __restrict__ Aw, const _Float16* __restrict__ Bw,
             const _Float16* __restrict__ Au, const _Float16* __restrict__ Bu,
             float* __restrict__ Sd, _Float16* __restrict__ mhq,
             const float* __restrict__ AAv, const float* __restrict__ BBv,
             const float* __restrict__ tbias,
             const float* __restrict__ p_log_scale,
             const float* __restrict__ p_log_eps, int M, int N) {
  __shared__ _Float16 As[BM][LDK];
  __shared__ _Float16 Bs[BN][LDK];
  const int tid = threadIdx.x;
  const int bm = blockIdx.y * BM;
  const int bn = blockIdx.x * BN;
  const int srow = tid >> 1;
  const int skb = (tid & 1) << 4;
  const int wave = tid >> 6;
  const int lane = tid & 63;
  const int wm = (wave >> 1) << 6;
  const int wn = (wave & 1) << 6;
  const int lm = lane & 15;
  const int quad = lane >> 4;
  const int ra = bm + srow;
  const int rb = bn + srow;
  f32x4 accP[4][4];
#pragma unroll
  for (int i = 0; i < 4; ++i)
#pragma unroll
    for (int j = 0; j < 4; ++j) accP[i][j] = (f32x4){0.f, 0.f, 0.f, 0.f};
  // ---- pass 1: P over RR (6 k-steps) ----
  for (int k0 = 0; k0 < RR; k0 += BK) {
    f16x8 a0 = (f16x8)(_Float16)0, a1 = a0, b0 = a0, b1 = a0;
    if (ra < M) {
      const f16x8* p = (const f16x8*)(Au + (size_t)ra * RR + k0 + skb);
      a0 = p[0]; a1 = p[1];
    }
    if (rb < N) {
      const f16x8* p = (const f16x8*)(Bu + (size_t)rb * RR + k0 + skb);
      b0 = p[0]; b1 = p[1];
    }
    __syncthreads();
    *(f16x8*)&As[srow][skb] = a0; *(f16x8*)&As[srow][skb + 8] = a1;
    *(f16x8*)&Bs[srow][skb] = b0; *(f16x8*)&Bs[srow][skb + 8] = b1;
    __syncthreads();
    f16x8 Af[4], Bf[4];
#pragma unroll
    for (int i = 0; i < 4; ++i) {
      Af[i] = *(const f16x8*)&As[wm + i * 16 + lm][quad * 8];
      Bf[i] = *(const f16x8*)&Bs[wn + i * 16 + lm][quad * 8];
    }
#pragma unroll
    for (int i = 0; i < 4; ++i)
#pragma unroll
      for (int j = 0; j < 4; ++j)
        accP[i][j] = __builtin_amdgcn_mfma_f32_16x16x32_f16(Af[i], Bf[j], accP[i][j], 0, 0, 0);
  }
  // ---- pass 2: S over DD (24 k-steps) ----
  f32x4 accS[4][4];
#pragma unroll
  for (int i = 0; i < 4; ++i)
#pragma unroll
    for (int j = 0; j < 4; ++j) accS[i][j] = (f32x4){0.f, 0.f, 0.f, 0.f};
  for (int k0 = 0; k0 < DD; k0 += BK) {
    f16x8 a0 = (f16x8)(_Float16)0, a1 = a0, b0 = a0, b1 = a0;
    if (ra < M) {
      const f16x8* p = (const f16x8*)(Aw + (size_t)ra * DD + k0 + skb);
      a0 = p[0]; a1 = p[1];
    }
    if (rb < N) {
      const f16x8* p = (const f16x8*)(Bw + (size_t)rb * DD + k0 + skb);
      b0 = p[0]; b1 = p[1];
    }
    __syncthreads();
    *(f16x8*)&As[srow][skb] = a0; *(f16x8*)&As[srow][skb + 8] = a1;
    *(f16x8*)&Bs[srow][skb] = b0; *(f16x8*)&Bs[srow][skb + 8] = b1;
    __syncthreads();
    f16x8 Af[4], Bf[4];
#pragma unroll
    for (int i = 0; i < 4; ++i) {
      Af[i] = *(const f16x8*)&As[wm + i * 16 + lm][quad * 8];
      Bf[i] = *(const f16x8*)&Bs[wn + i * 16 + lm][quad * 8];
    }
#pragma unroll
    for (int i = 0; i < 4; ++i)
#pragma unroll
      for (int j = 0; j < 4; ++j)
        accS[i][j] = __builtin_amdgcn_mfma_f32_16x16x32_f16(Af[i], Bf[j], accS[i][j], 0, 0, 0);
  }
  // ---- epilogue ----
  float scale = fminf(expf(p_log_scale[0]), 20.f);
  float qs = L2E / get_eps(p_log_eps);  // mh -> q units
#pragma unroll
  for (int i = 0; i < 4; ++i)
#pragma unroll
    for (int j = 0; j < 4; ++j) {
      int col = bn + wn + j * 16 + lm;
      if (col >= N) continue;
      float BB = BBv[col];
#pragma unroll
      for (int r = 0; r < 4; ++r) {
        int row = bm + wm + i * 16 + quad * 4 + r;  // < 512 always
        float S = accS[i][j][r];
        float mh = fmaxf(AAv[row] + BB - 2.f * (S + accP[i][j][r]), 0.f);
        Sd[(size_t)row * N + col] = fmaf(scale, S, tbias[row]);
        mhq[(size_t)row * VP + col] = (_Float16)(mh * qs);
      }
    }
}

// ---------------------------------------------------------------------------
// P-GEMM (aU16 @ wU16^T, Kd=192) + fused epilogue (tight-workspace fallback):
//   Sd <- scale*S + bias ;  mhq <- fp16( relu(AA+BB-2(S+P)) * L2E/eps )
// ---------------------------------------------------------------------------
__global__ __launch_bounds__(256, 2)
void gemm16_p(const _Float16* __restrict__ A, const _Float16* __restrict__ B,
              float* __restrict__ Sd, _Float16* __restrict__ mhq,
              const float* __restrict__ AAv, const float* __restrict__ BBv,
              const float* __restrict__ tbias,
              const float* __restrict__ p_log_scale,
              const float* __restrict__ p_log_eps, int M, int N, int Kd) {
  __shared__ _Float16 As[BM][LDK];
  __shared__ _Float16 Bs[BN][LDK];
  const int tid = threadIdx.x;
  const int bm = blockIdx.y * BM;
  const int bn = blockIdx.x * BN;
  const int srow = tid >> 1;
  const int skb = (tid & 1) << 4;
  const int wave = tid >> 6;
  const int lane = tid & 63;
  const int wm = (wave >> 1) << 6;
  const int wn = (wave & 1) << 6;
  const int lm = lane & 15;
  const int quad = lane >> 4;
  f32x4 acc[4][4];
#pragma unroll
  for (int i = 0; i < 4; ++i)
#pragma unroll
    for (int j = 0; j < 4; ++j) acc[i][j] = (f32x4){0.f, 0.f, 0.f, 0.f};
  const int ra = bm + srow;
  const int rb = bn + srow;
  for (int k0 = 0; k0 < Kd; k0 += BK) {
    f16x8 a0 = (f16x8)(_Float16)0, a1 = a0, b0 = a0, b1 = a0;
    if (ra < M) {
      const f16x8* p = (const f16x8*)(A + (size_t)ra * Kd + k0 + skb);
      a0 = p[0]; a1 = p[1];
    }
    if (rb < N) {
      const f16x8* p = (const f16x8*)(B + (size_t)rb * Kd + k0 + skb);
      b0 = p[0]; b1 = p[1];
    }
    __syncthreads();
    *(f16x8*)&As[srow][skb] = a0; *(f16x8*)&As[srow][skb + 8] = a1;
    *(f16x8*)&Bs[srow][skb] = b0; *(f16x8*)&Bs[srow][skb + 8] = b1;
    __syncthreads();
    f16x8 Af[4], Bf[4];
#pragma unroll
    for (int i = 0; i < 4; ++i) {
      Af[i] = *(const f16x8*)&As[wm + i * 16 + lm][quad * 8];
      Bf[i] = *(const f16x8*)&Bs[wn + i * 16 + lm][quad * 8];
    }
#pragma unroll
    for (int i = 0; i < 4; ++i)
#pragma unroll
      for (int j = 0; j < 4; ++j)
        acc[i][j] = __builtin_amdgcn_mfma_f32_16x16x32_f16(Af[i], Bf[j], acc[i][j], 0, 0, 0);
  }
  float scale = fminf(expf(p_log_scale[0]), 20.f);
  float qs = L2E / get_eps(p_log_eps);  // mh -> q units
#pragma unroll
  for (int i = 0; i < 4; ++i)
#pragma unroll
    for (int j = 0; j < 4; ++j) {
      int col = bn + wn + j * 16 + lm;
      if (col >= N) continue;
      float BB = BBv[col];
#pragma unroll
      for (int r = 0; r < 4; ++r) {
        int row = bm + wm + i * 16 + quad * 4 + r;  // < 512 always
        size_t idx = (size_t)row * N + col;
        float S = Sd[idx];
        float mh = fmaxf(AAv[row] + BB - 2.f * (S + acc[i][j][r]), 0.f);
        Sd[idx] = fmaf(scale, S, tbias[row]);
        mhq[(size_t)row * VP + col] = (_Float16)(mh * qs);
      }
    }
}

// ---------------------------------------------------------------------------
// out[r] = 1 + sum(X16[r,:]^2), cols <= 256
// ---------------------------------------------------------------------------
__global__ __launch_bounds__(256)
void row_sumsq16(const _Float16* __restrict__ X, float* __restrict__ out, int cols) {
  int r = blockIdx.x;
  int t = threadIdx.x;
  float x = (t < cols) ? (float)X[(size_t)r * cols + t] : 0.f;
  __shared__ float red[256];
  red[t] = x * x;
  __syncthreads();
  for (int off = 128; off > 0; off >>= 1) {
    if (t < off) red[t] += red[t + off];
    __syncthreads();
  }
  if (t == 0) out[r] = 1.0f + red[0];
}

// ---------------------------------------------------------------------------
// Sinkhorn row (log2 domain): lu2[k] = -(Mv2 + log2(sum_v 2^(lv2[v]-Mv2-q)))
// ---------------------------------------------------------------------------
__global__ __launch_bounds__(1024)
void sink_row(const _Float16* __restrict__ mhq, const float* __restrict__ lv2,
              float* __restrict__ lu2,
              const unsigned* __restrict__ Mv_slot, unsigned* __restrict__ Mu_slot) {
  int k = blockIdx.x;
  int t = threadIdx.x;
  float Mv2 = dec_f(*Mv_slot);
  const _Float16* row = mhq + (size_t)k * VP;
  float s[8] = {0.f, 0.f, 0.f, 0.f, 0.f, 0.f, 0.f, 0.f};
#pragma unroll
  for (int j = 0; j < 6; ++j) {
    int v = j * 8192 + t * 8;
    f16x8 hv = *(const f16x8*)(row + v);
    float4 l0 = *(const float4*)(lv2 + v);
    float4 l1 = *(const float4*)(lv2 + v + 4);
    float lv[8] = {l0.x, l0.y, l0.z, l0.w, l1.x, l1.y, l1.z, l1.w};
#pragma unroll
    for (int i = 0; i < 8; ++i)
      s[i] += fast_exp2(lv[i] - Mv2 - (float)hv[i]);
  }
  {
    int v = 49152 + t;
    s[0] += fast_exp2(lv2[v] - Mv2 - (float)row[v]);
    v = 50176 + t;
    if (v < VV) s[1] += fast_exp2(lv2[v] - Mv2 - (float)row[v]);
  }
  float sum = ((s[0] + s[1]) + (s[2] + s[3])) + ((s[4] + s[5]) + (s[6] + s[7]));
  __shared__ float red[1024];
  red[t] = sum;
  __syncthreads();
  for (int off = 512; off > 0; off >>= 1) {
    if (t < off) red[t] += red[t + off];
    __syncthreads();
  }
  if (t == 0) {
    float lu = -(Mv2 + log2f(red[0]));
    lu2[k] = lu;
    atomicMax(Mu_slot, enc_f(lu));
  }
}

// ---------------------------------------------------------------------------
// Sinkhorn col: lv2[v] = -(Mu2 + log2(sum_k 2^(lu2[k]-Mu2-q)))
// ---------------------------------------------------------------------------
__global__ __launch_bounds__(256)
void sink_col(const _Float16* __restrict__ mhq, const float* __restrict__ lu2,
              float* __restrict__ lv2,
              const unsigned* __restrict__ Mu_slot, unsigned* __restrict__ Mv_next) {
  __shared__ float lu_s[KK];
  int t = threadIdx.x;
  for (int i = t; i < KK; i += 256) lu_s[i] = lu2[i];
  __syncthreads();
  float Mu2 = dec_f(*Mu_slot);
  int cp = blockIdx.x * 64 + (t & 63);
  int v0 = cp * 2;
  int kc = t >> 6;
  float sA = 0.f, sB = 0.f;
  if (v0 < VV) {
    const _Float16* base = mhq + v0;
#pragma unroll 4
    for (int k = kc * 128; k < kc * 128 + 128; ++k) {
      f16x2 hv = *(const f16x2*)(base + (size_t)k * VP);
      float lu = lu_s[k] - Mu2;
      sA += fast_exp2(lu - (float)hv[0]);
      sB += fast_exp2(lu - (float)hv[1]);
    }
  }
  __shared__ float pA[256], pB[256];
  __shared__ unsigned em[64];
  pA[t] = sA; pB[t] = sB;
  __syncthreads();
  if (t < 64) {
    unsigned e = ENC_NEG_INF;
    if (v0 < VV) {
      float a = (pA[t] + pA[t + 64]) + (pA[t + 128] + pA[t + 192]);
      float lv = -(Mu2 + log2f(a));
      lv2[v0] = lv;
      e = enc_f(lv);
      if (v0 + 1 < VV) {
        float b = (pB[t] + pB[t + 64]) + (pB[t + 128] + pB[t + 192]);
        float lv1 = -(Mu2 + log2f(b));
        lv2[v0 + 1] = lv1;
        unsigned e1 = enc_f(lv1);
        if (e1 > e) e = e1;
      }
    }
    em[t] = e;
  }
  __syncthreads();
  for (int off = 32; off > 0; off >>= 1) {
    if (t < off && em[t + off] > em[t]) em[t] = em[t + off];
    __syncthreads();
  }
  if (t == 0) atomicMax(Mv_next, em[0]);
}

// ---------------------------------------------------------------------------
// final pass 1: row_s[k] = sum_v exp(logit - 30)   (logits clipped at +-30)
//  logit x = d - c2*q + c3*(lu2+lv2);  c2=(LAM*eps+GAM)/L2E, c3=GAM/L2E
// ---------------------------------------------------------------------------
__global__ __launch_bounds__(1024)
void final_sum(const float* __restrict__ direct, const _Float16* __restrict__ mhq,
               const float* __restrict__ lu2, const float* __restrict__ lv2,
               float* __restrict__ row_s, const float* __restrict__ p_log_eps) {
  int k = blockIdx.x;
  int t = threadIdx.x;
  float eps = get_eps(p_log_eps);
  float c2 = (LAM * eps + GAM) / L2E;
  float c3 = GAM / L2E;
  float base_lu = c3 * lu2[k];
  const float* drow = direct + (size_t)k * VV;
  const _Float16* mrow = mhq + (size_t)k * VP;
  float s[8] = {0.f, 0.f, 0.f, 0.f, 0.f, 0.f, 0.f, 0.f};
#pragma unroll
  for (int j = 0; j < 6; ++j) {
    int v = j * 8192 + t * 8;
    f16x8 hv = *(const f16x8*)(mrow + v);
    float4 d0 = *(const float4*)(drow + v);
    float4 d1 = *(const float4*)(drow + v + 4);
    float4 l0 = *(const float4*)(lv2 + v);
    float4 l1 = *(const float4*)(lv2 + v + 4);
    float dd[8] = {d0.x, d0.y, d0.z, d0.w, d1.x, d1.y, d1.z, d1.w};
    float lv[8] = {l0.x, l0.y, l0.z, l0.w, l1.x, l1.y, l1.z, l1.w};
#pragma unroll
    for (int i = 0; i < 8; ++i) {
      float x = fmaf(-c2, (float)hv[i], fmaf(c3, lv[i], dd[i] + base_lu));
      x = fminf(30.f, fmaxf(-30.f, x));
      s[i] += fast_exp2(fmaf(x, L2E, -30.f * L2E));
    }
  }
  {
    int v = 49152 + t;
    float x = fmaf(-c2, (float)mrow[v], fmaf(c3, lv2[v], drow[v] + base_lu));
    x = fminf(30.f, fmaxf(-30.f, x));
    s[0] += fast_exp2(fmaf(x, L2E, -30.f * L2E));
    v = 50176 + t;
    if (v < VV) {
      x = fmaf(-c2, (float)mrow[v], fmaf(c3, lv2[v], drow[v] + base_lu));
      x = fminf(30.f, fmaxf(-30.f, x));
      s[1] += fast_exp2(fmaf(x, L2E, -30.f * L2E));
    }
  }
  float sum = ((s[0] + s[1]) + (s[2] + s[3])) + ((s[4] + s[5]) + (s[6] + s[7]));
  __shared__ float red[1024];
  red[t] = sum;
  __syncthreads();
  for (int off = 512; off > 0; off >>= 1) {
    if (t < off) red[t] += red[t + off];
    __syncthreads();
  }
  if (t == 0) row_s[k] = red[0];
}

// ---------------------------------------------------------------------------
// final pass 2: out[k,v] = exp(logit - 30) / row_s[k]
// ---------------------------------------------------------------------------
__global__ __launch_bounds__(256)
void final_write(float* __restrict__ out, const _Float16* __restrict__ mhq,
                 const float* __restrict__ lu2, const float* __restrict__ lv2,
                 const float* __restrict__ row_s, const float* __restrict__ p_log_eps) {
  int v = blockIdx.x * 256 + threadIdx.x;
  int k = blockIdx.y;
  if (v >= VV) return;
  float eps = get_eps(p_log_eps);
  float c2 = (LAM * eps + GAM) / L2E;
  float c3 = GAM / L2E;
  size_t idx = (size_t)k * VV + v;
  float x = fmaf(-c2, (float)mhq[(size_t)k * VP + v],
                 fmaf(c3, lv2[v], out[idx] + c3 * lu2[k]));
  x = fminf(30.f, fmaxf(-30.f, x));
  out[idx] = fast_exp2(fmaf(x, L2E, -30.f * L2E)) / row_s[k];
}

// ---------------------------------------------------------------------------
// launch
// ---------------------------------------------------------------------------
extern "C" void kernel_launch(void* const* d_in, const int* in_sizes, int n_in,
                              void* d_out, int out_size, void* d_ws, size_t ws_size,
                              hipStream_t stream) {
  (void)in_sizes; (void)n_in; (void)out_size;
  const float* WE        = (const float*)d_in[0];
  const float* anchors   = (const float*)d_in[1];
  const float* MU        = (const float*)d_in[2];
  const float* log_eps   = (const float*)d_in[3];
  const float* log_scale = (const float*)d_in[4];
  const float* tbias     = (const float*)d_in[5];
  const float* Wp        = (const float*)d_in[6];
  float* out = (float*)d_out;

  // workspace layout. If ws_size allows, give mhq its own region (required by
  // the fused S+P GEMM, which reads w16 while writing mhq). Otherwise fall
  // back to the alias layout (mhq over w16, dead-after-S) + two-kernel path.
  const size_t H_W16 = (size_t)VV * DD;   // 38,597,376 halfs
  const size_t H_MHQ = (size_t)KK * VP;   // 25,739,264 halfs
  const size_t H_WU  = (size_t)VV * RR;
  const size_t H_A16 = (size_t)KK * DD;
  const size_t H_AU  = (size_t)KK * RR;
  const size_t H_UT  = (size_t)RR * DD;
  const size_t FB_FLOATS = 102064 + 32;   // fp32 region incl. slots
  const size_t need_roomy =
      2 * (H_W16 + H_MHQ + H_WU + H_A16 + H_AU + H_UT) + 4 * FB_FLOATS;
  const bool roomy = ws_size >= need_roomy;

  _Float16* hb = (_Float16*)d_ws;
  _Float16* w16 = hb;
  size_t ho = H_W16;
  _Float16* mhq;
  if (roomy) { mhq = hb + ho; ho += H_MHQ; }
  else       { mhq = hb; }                 // alias w16 (dead after S GEMM)
  _Float16* wU16 = hb + ho; ho += H_WU;
  _Float16* a16  = hb + ho; ho += H_A16;
  _Float16* aU16 = hb + ho; ho += H_AU;
  _Float16* Ut16 = hb + ho; ho += H_UT;
  float* fb = (float*)(hb + ho);
  float* BBv   = fb;           // 50264
  float* AAv   = fb + 50264;   // 512
  float* lu2   = fb + 50776;   // 512
  float* lv2   = fb + 51288;   // 50264
  float* row_s = fb + 101552;  // 512
  unsigned* slots = (unsigned*)(fb + 102064);  // 25
  unsigned* Mv_slots = slots;
  unsigned* Mu_slots = slots + 12;
  unsigned* eye_flag = slots + 24;

  const int VB = (VV + 255) / 256;      // 197
  const int MB_V = (VV + BM - 1) / BM;  // 393

  prep<<<1286, 256, 0, stream>>>(MU, lv2, slots, anchors, Ut16, a16);
  check_eye<<<(DD * DD + 255) / 256, 256, 0, stream>>>(Wp, eye_flag);
  // fallback only (no-op when Wp == I): w16 = fp16(WE @ Wp^T)
  gemm_we_fallback<<<dim3(DD / BN, MB_V), 256, 0, stream>>>(WE, Wp, w16, VV, DD, DD, eye_flag);
  norm_w<<<VV, 256, 0, stream>>>(WE, w16, eye_flag);
  // wU16 = w16 @ Ut16^T ; aU16 = a16 @ Ut16^T
  gemm16<1><<<dim3(2, MB_V), 256, 0, stream>>>(w16, Ut16, wU16, VV, RR, DD);
  gemm16<1><<<dim3(2, 4), 256, 0, stream>>>(a16, Ut16, aU16, KK, RR, DD);
  row_sumsq16<<<VV, 256, 0, stream>>>(wU16, BBv, RR);
  row_sumsq16<<<KK, 256, 0, stream>>>(aU16, AAv, RR);
  if (roomy) {
    // fused: S+P in one kernel, no 103 MB S round-trip through HBM
    gemm_sp<<<dim3(MB_V, 4), 256, 0, stream>>>(a16, w16, aU16, wU16, out, mhq,
                                               AAv, BBv, tbias, log_scale,
                                               log_eps, KK, VV);
  } else {
    // S = a16 @ w16^T -> out (fp32)
    gemm16<0><<<dim3(MB_V, 4), 256, 0, stream>>>(a16, w16, out, KK, VV, DD);
    // P GEMM + fused epilogue -> out = scale*S+bias, mhq = fp16(mh*L2E/eps)
    gemm16_p<<<dim3(MB_V, 4), 256, 0, stream>>>(aU16, wU16, out, mhq, AAv, BBv,
                                                tbias, log_scale, log_eps, KK, VV, RR);
  }
  for (int it = 0; it < 10; ++it) {
    sink_row<<<KK, 1024, 0, stream>>>(mhq, lv2, lu2, Mv_slots + it, Mu_slots + it);
    sink_col<<<MB_V, 256, 0, stream>>>(mhq, lu2, lv2, Mu_slots + it, Mv_slots + it + 1);
  }
  final_sum<<<KK, 1024, 0, stream>>>(out, mhq, lu2, lv2, row_s, log_eps);
  final_write<<<dim3(VB, KK), 256, 0, stream>>>(out, mhq, lu2, lv2, row_s, log_eps);
}

// Round 2
// 907.649 us; speedup vs baseline: 1.0239x; 1.0239x over previous
//
#include <hip/hip_runtime.h>
#include <math.h>

#define KK 512
#define VV 50257
#define VP 50272   // padded mhq row stride (halfs)
#define DD 768
#define RR 192

#define LAM 0.3f
#define GAM 0.3f
#define L2E 1.44269504088896340736f
#define ENC_NEG_INF 0x007FFFFFu

typedef __bf16 bf16x8 __attribute__((ext_vector_type(8)));
typedef _Float16 f16x8 __attribute__((ext_vector_type(8)));
typedef _Float16 f16x2 __attribute__((ext_vector_type(2)));
typedef unsigned short u16x8 __attribute__((ext_vector_type(8)));
typedef float f32x4 __attribute__((ext_vector_type(4)));

// ---------------------------------------------------------------------------
// helpers
// ---------------------------------------------------------------------------
static __device__ __forceinline__ float get_eps(const float* p_log_eps) {
  return log1pf(expf(p_log_eps[0])) + 0.001f;  // softplus(log_eps)+1e-3
}

static __device__ __forceinline__ float fast_exp2(float x) {
  return __builtin_amdgcn_exp2f(x);  // v_exp_f32 (2^x)
}

// order-preserving float<->unsigned encode for atomicMax
static __device__ __forceinline__ unsigned enc_f(float f) {
  unsigned u = __builtin_bit_cast(unsigned, f);
  return (u & 0x80000000u) ? ~u : (u | 0x80000000u);
}
static __device__ __forceinline__ float dec_f(unsigned e) {
  unsigned u = (e & 0x80000000u) ? (e ^ 0x80000000u) : ~e;
  return __builtin_bit_cast(float, u);
}

// fp32 -> bf16 rne (for the non-eye fallback GEMM only)
static __device__ __forceinline__ unsigned short f2bf(float x) {
  unsigned u = __builtin_bit_cast(unsigned, x);
  u += 0x7fffu + ((u >> 16) & 1u);
  return (unsigned short)(u >> 16);
}
static __device__ __forceinline__ float bf2f(unsigned short h) {
  unsigned u = ((unsigned)h) << 16;
  return __builtin_bit_cast(float, u);
}

// async global->LDS DMA, 16 B per lane. LDS dest is wave-uniform base +
// lane*16 (m104); global src is per-lane.
static __device__ __forceinline__ void gload_lds16(const void* g, void* l) {
  __builtin_amdgcn_global_load_lds(
      (const __attribute__((address_space(1))) unsigned int*)g,
      (__attribute__((address_space(3))) unsigned int*)l, 16, 0, 0);
}

// ---------------------------------------------------------------------------
// prep: fused small-kernel pass.
//  blocks [0,576):    Ut16[r,d] = fp16(U[d,r])
//  blocks [576,773):  lv2 = 0 (50264 incl pad)
//  block 773:         slots init (Mv/Mu maxima, eye flag)
//  blocks [774,1286): a16 = fp16(normalize(anchors)), one block per row
// slots: [0..11]=Mv2, [12..23]=Mu2, [24]=eye_flag
// ---------------------------------------------------------------------------
__global__ __launch_bounds__(256)
void prep(const float* __restrict__ U, float* __restrict__ lv2,
          unsigned* __restrict__ slots, const float* __restrict__ anchors,
          _Float16* __restrict__ Ut16, _Float16* __restrict__ a16) {
  int bid = blockIdx.x;
  int t = threadIdx.x;
  if (bid < 576) {
    int idx = bid * 256 + t;
    int r = idx / DD;
    int d = idx - r * DD;
    Ut16[idx] = (_Float16)U[(size_t)d * RR + r];
  } else if (bid < 773) {
    int i = (bid - 576) * 256 + t;
    if (i < 50264) lv2[i] = 0.f;
  } else if (bid == 773) {
    if (t < 24) slots[t] = (t == 0) ? 0x80000000u : ENC_NEG_INF;  // enc(0), enc(-inf)
    if (t == 24) slots[24] = 1u;                                  // eye_flag
  } else {
    int r = bid - 774;
    const float* x = anchors + (size_t)r * DD;
    float v0 = x[t], v1 = x[t + 256], v2 = x[t + 512];
    __shared__ float red[256];
    red[t] = v0 * v0 + v1 * v1 + v2 * v2;
    __syncthreads();
    for (int off = 128; off > 0; off >>= 1) {
      if (t < off) red[t] += red[t + off];
      __syncthreads();
    }
    float inv = 1.0f / fmaxf(sqrtf(red[0]), 1e-12f);
    _Float16* y = a16 + (size_t)r * DD;
    y[t] = (_Float16)(v0 * inv);
    y[t + 256] = (_Float16)(v1 * inv);
    y[t + 512] = (_Float16)(v2 * inv);
  }
}

// ---------------------------------------------------------------------------
// check Wp == I (exact); clears eye flag on mismatch
// ---------------------------------------------------------------------------
__global__ __launch_bounds__(256)
void check_eye(const float* __restrict__ Wp, unsigned* __restrict__ flag) {
  int i = blockIdx.x * 256 + threadIdx.x;
  if (i >= DD * DD) return;
  int r = i / DD;
  int c = i - r * DD;
  float expect = (r == c) ? 1.f : 0.f;
  if (Wp[i] != expect) atomicAnd(flag, 0u);
}

// ---------------------------------------------------------------------------
// FALLBACK ONLY (Wp != I): split-bf16 3-term GEMM w_raw = WE @ Wp^T -> fp16.
// When *eyeflag, returns immediately (norm_w reads WE directly).
// ---------------------------------------------------------------------------
#define BM 128
#define BN 128
#define BK 32
#define LDKB 40  // bf16 fallback LDS stride
#define LDK 40   // fp16 LDS stride (pad -> 2-way banks, free)

__global__ __launch_bounds__(256, 2)
void gemm_we_fallback(const float* __restrict__ A, const float* __restrict__ B,
                      _Float16* __restrict__ C, int M, int N, int Kd,
                      const unsigned* __restrict__ eyeflag) {
  if (*eyeflag) return;
  __shared__ unsigned short As[2][BM][LDKB];
  __shared__ unsigned short Bs[2][BN][LDKB];
  const int tid = threadIdx.x;
  const int bm = blockIdx.y * BM;
  const int bn = blockIdx.x * BN;
  const int srow = tid >> 1;
  const int skb = (tid & 1) << 4;
  const int wave = tid >> 6;
  const int lane = tid & 63;
  const int wm = (wave >> 1) << 6;
  const int wn = (wave & 1) << 6;
  const int lm = lane & 15;
  const int quad = lane >> 4;
  f32x4 acc[4][4];
#pragma unroll
  for (int i = 0; i < 4; ++i)
#pragma unroll
    for (int j = 0; j < 4; ++j) acc[i][j] = (f32x4){0.f, 0.f, 0.f, 0.f};
  const int ra = bm + srow;
  const int rb = bn + srow;
  for (int k0 = 0; k0 < Kd; k0 += BK) {
    float va[16], vb[16];
    if (ra < M) {
      const float4* p = (const float4*)(A + (size_t)ra * Kd + k0 + skb);
      ((float4*)va)[0] = p[0]; ((float4*)va)[1] = p[1];
      ((float4*)va)[2] = p[2]; ((float4*)va)[3] = p[3];
    } else {
#pragma unroll
      for (int q = 0; q < 16; ++q) va[q] = 0.f;
    }
    if (rb < N) {
      const float4* p = (const float4*)(B + (size_t)rb * Kd + k0 + skb);
      ((float4*)vb)[0] = p[0]; ((float4*)vb)[1] = p[1];
      ((float4*)vb)[2] = p[2]; ((float4*)vb)[3] = p[3];
    } else {
#pragma unroll
      for (int q = 0; q < 16; ++q) vb[q] = 0.f;
    }
    __syncthreads();
    {
      u16x8 h0, h1, l0, l1;
#pragma unroll
      for (int q = 0; q < 8; ++q) {
        unsigned short h = f2bf(va[q]);
        h0[q] = h; l0[q] = f2bf(va[q] - bf2f(h));
        h = f2bf(va[q + 8]);
        h1[q] = h; l1[q] = f2bf(va[q + 8] - bf2f(h));
      }
      *(u16x8*)&As[0][srow][skb] = h0; *(u16x8*)&As[0][srow][skb + 8] = h1;
      *(u16x8*)&As[1][srow][skb] = l0; *(u16x8*)&As[1][srow][skb + 8] = l1;
#pragma unroll
      for (int q = 0; q < 8; ++q) {
        unsigned short h = f2bf(vb[q]);
        h0[q] = h; l0[q] = f2bf(vb[q] - bf2f(h));
        h = f2bf(vb[q + 8]);
        h1[q] = h; l1[q] = f2bf(vb[q + 8] - bf2f(h));
      }
      *(u16x8*)&Bs[0][srow][skb] = h0; *(u16x8*)&Bs[0][srow][skb + 8] = h1;
      *(u16x8*)&Bs[1][srow][skb] = l0; *(u16x8*)&Bs[1][srow][skb + 8] = l1;
    }
    __syncthreads();
    bf16x8 Ah[4], Al[4], Bh[4], Bl[4];
#pragma unroll
    for (int i = 0; i < 4; ++i) {
      Ah[i] = *(const bf16x8*)&As[0][wm + i * 16 + lm][quad * 8];
      Al[i] = *(const bf16x8*)&As[1][wm + i * 16 + lm][quad * 8];
      Bh[i] = *(const bf16x8*)&Bs[0][wn + i * 16 + lm][quad * 8];
      Bl[i] = *(const bf16x8*)&Bs[1][wn + i * 16 + lm][quad * 8];
    }
#pragma unroll
    for (int i = 0; i < 4; ++i)
#pragma unroll
      for (int j = 0; j < 4; ++j) {
        acc[i][j] = __builtin_amdgcn_mfma_f32_16x16x32_bf16(Ah[i], Bh[j], acc[i][j], 0, 0, 0);
        acc[i][j] = __builtin_amdgcn_mfma_f32_16x16x32_bf16(Ah[i], Bl[j], acc[i][j], 0, 0, 0);
        acc[i][j] = __builtin_amdgcn_mfma_f32_16x16x32_bf16(Al[i], Bh[j], acc[i][j], 0, 0, 0);
      }
  }
#pragma unroll
  for (int i = 0; i < 4; ++i)
#pragma unroll
    for (int j = 0; j < 4; ++j) {
      int col = bn + wn + j * 16 + lm;
#pragma unroll
      for (int r = 0; r < 4; ++r) {
        int row = bm + wm + i * 16 + quad * 4 + r;
        if (row < M && col < N) C[(size_t)row * N + col] = (_Float16)acc[i][j][r];
      }
    }
}

// ---------------------------------------------------------------------------
// norm_w: w16[r,:] = fp16(normalize(src[r,:])), src = eye ? WE(f32) : w16(f16)
// ---------------------------------------------------------------------------
__global__ __launch_bounds__(256)
void norm_w(const float* __restrict__ WE, _Float16* __restrict__ w16,
            const unsigned* __restrict__ eyeflag) {
  int r = blockIdx.x;
  int t = threadIdx.x;
  float v0, v1, v2;
  if (*eyeflag) {
    const float* x = WE + (size_t)r * DD;
    v0 = x[t]; v1 = x[t + 256]; v2 = x[t + 512];
  } else {
    const _Float16* x = w16 + (size_t)r * DD;
    v0 = (float)x[t]; v1 = (float)x[t + 256]; v2 = (float)x[t + 512];
  }
  __shared__ float red[256];
  red[t] = v0 * v0 + v1 * v1 + v2 * v2;
  __syncthreads();
  for (int off = 128; off > 0; off >>= 1) {
    if (t < off) red[t] += red[t + off];
    __syncthreads();
  }
  float inv = 1.0f / fmaxf(sqrtf(red[0]), 1e-12f);
  _Float16* y = w16 + (size_t)r * DD;
  y[t] = (_Float16)(v0 * inv);
  y[t + 256] = (_Float16)(v1 * inv);
  y[t + 512] = (_Float16)(v2 * inv);
}

// ---------------------------------------------------------------------------
// fp16 single-term MFMA GEMM: C[M,N] = A[M,Kd]*B[N,Kd]^T. 128x128 tile, BK=32,
// 4 waves x 4x4 frags of mfma_f32_16x16x32_f16. F16OUT: fp16 or fp32 C.
// (reg-staged; used for the small R-projection GEMMs and the fallback path)
// ---------------------------------------------------------------------------
template <int F16OUT>
__global__ __launch_bounds__(256, 2)
void gemm16(const _Float16* __restrict__ A, const _Float16* __restrict__ B,
            void* __restrict__ Cv, int M, int N, int Kd) {
  __shared__ _Float16 As[BM][LDK];
  __shared__ _Float16 Bs[BN][LDK];
  const int tid = threadIdx.x;
  const int bm = blockIdx.y * BM;
  const int bn = blockIdx.x * BN;
  const int srow = tid >> 1;
  const int skb = (tid & 1) << 4;
  const int wave = tid >> 6;
  const int lane = tid & 63;
  const int wm = (wave >> 1) << 6;
  const int wn = (wave & 1) << 6;
  const int lm = lane & 15;
  const int quad = lane >> 4;
  f32x4 acc[4][4];
#pragma unroll
  for (int i = 0; i < 4; ++i)
#pragma unroll
    for (int j = 0; j < 4; ++j) acc[i][j] = (f32x4){0.f, 0.f, 0.f, 0.f};
  const int ra = bm + srow;
  const int rb = bn + srow;
  for (int k0 = 0; k0 < Kd; k0 += BK) {
    f16x8 a0 = (f16x8)(_Float16)0, a1 = a0, b0 = a0, b1 = a0;
    if (ra < M) {
      const f16x8* p = (const f16x8*)(A + (size_t)ra * Kd + k0 + skb);
      a0 = p[0]; a1 = p[1];
    }
    if (rb < N) {
      const f16x8* p = (const f16x8*)(B + (size_t)rb * Kd + k0 + skb);
      b0 = p[0]; b1 = p[1];
    }
    __syncthreads();
    *(f16x8*)&As[srow][skb] = a0; *(f16x8*)&As[srow][skb + 8] = a1;
    *(f16x8*)&Bs[srow][skb] = b0; *(f16x8*)&Bs[srow][skb + 8] = b1;
    __syncthreads();
    f16x8 Af[4], Bf[4];
#pragma unroll
    for (int i = 0; i < 4; ++i) {
      Af[i] = *(const f16x8*)&As[wm + i * 16 + lm][quad * 8];
      Bf[i] = *(const f16x8*)&Bs[wn + i * 16 + lm][quad * 8];
    }
#pragma unroll
    for (int i = 0; i < 4; ++i)
#pragma unroll
      for (int j = 0; j < 4; ++j)
        acc[i][j] = __builtin_amdgcn_mfma_f32_16x16x32_f16(Af[i], Bf[j], acc[i][j], 0, 0, 0);
  }
#pragma unroll
  for (int i = 0; i < 4; ++i)
#pragma unroll
    for (int j = 0; j < 4; ++j) {
      int col = bn + wn + j * 16 + lm;
#pragma unroll
      for (int r = 0; r < 4; ++r) {
        int row = bm + wm + i * 16 + quad * 4 + r;
        if (row < M && col < N) {
          if (F16OUT)
            ((_Float16*)Cv)[(size_t)row * N + col] = (_Float16)acc[i][j][r];
          else
            ((float*)Cv)[(size_t)row * N + col] = acc[i][j][r];
        }
      }
    }
}

// ---------------------------------------------------------------------------
// FUSED S+P GEMM v2 (roomy path): global_load_lds staging (m97 structure).
//   accP = aU16 @ wU16^T (Kd=RR), accS = a16 @ w16^T (Kd=DD), then epilogue
//   Sd <- scale*S + bias ;  mhq <- fp16( relu(AA+BB-2(S+P)) * L2E/eps )
// Staging: linear LDS [128][32] halfs; DMA dest is wave-uniform + lane*16 so
// the bank-conflict fix is a T2 XOR swizzle applied on the GLOBAL source
// granule (g' = g ^ ((row>>1)&3)) and the same XOR on the ds_read col
// (both-sides involution, rule #21). Linear would be 8-way (2.94x, m136);
// swizzled is 2-way (free).
// Grid is (bm=4, bn=393): the 4 bm-blocks sharing a B-tile are dispatch-
// adjacent -> B fetched from HBM once, hit 3x in L3.
// OOB B-rows (>= VV, last tile) are loaded unguarded: they land in the
// adjacent workspace region (readable) and their columns are masked at the
// epilogue store, so garbage never propagates.
// ---------------------------------------------------------------------------
__global__ __launch_bounds__(256, 2)
void gemm_sp(const _Float16* __restrict__ Aw, const _Float16* __restrict__ Bw,
             const _Float16* __restrict__ Au, const _Float16* __restrict__ Bu,
             float* __restrict__ Sd, _Float16* __restrict__ mhq,
             const float* __restrict__ AAv, const float* __restrict__ BBv,
             const float* __restrict__ tbias,
             const float* __restrict__ p_log_scale,
             const float* __restrict__ p_log_eps, int M, int N) {
  __shared__ _Float16 As[BM][32];   // linear, 8 KB
  __shared__ _Float16 Bs[BN][32];   // linear, 8 KB
  const int tid = threadIdx.x;
  const int bm = blockIdx.x * BM;   // K-rows: 4 blocks
  const int bn = blockIdx.y * BN;   // V-cols: 393 blocks
  const int wave = tid >> 6;
  const int lane = tid & 63;
  const int wm = (wave >> 1) << 6;
  const int wn = (wave & 1) << 6;
  const int lm = lane & 15;
  const int quad = lane >> 4;

  // staging geometry: tile = 8 chunks of 1024 B (16 rows x 4 granules of 16B).
  // wave w stages chunks {2w, 2w+1} of A and of B.
  const int c0 = wave * 2;
  const int r0 = c0 * 16 + (lane >> 2);   // row for chunk c0
  const int r1 = r0 + 16;                 // row for chunk c0+1
  const int gp = lane & 3;                // LDS granule position in row
  const int gg0 = gp ^ ((r0 >> 1) & 3);   // global granule (XOR swizzle)
  const int gg1 = gp ^ ((r1 >> 1) & 3);
  _Float16* ldsA0 = &As[0][0] + c0 * 512;  // 512 halfs = 1024 B per chunk
  _Float16* ldsA1 = ldsA0 + 512;
  _Float16* ldsB0 = &Bs[0][0] + c0 * 512;
  _Float16* ldsB1 = ldsB0 + 512;

  f32x4 accP[4][4];
#pragma unroll
  for (int i = 0; i < 4; ++i)
#pragma unroll
    for (int j = 0; j < 4; ++j) accP[i][j] = (f32x4){0.f, 0.f, 0.f, 0.f};

  // ---- pass 1: P over RR (6 k-steps) ----
  {
    const _Float16* pa0 = Au + (size_t)(bm + r0) * RR + gg0 * 8;
    const _Float16* pa1 = Au + (size_t)(bm + r1) * RR + gg1 * 8;
    const _Float16* pb0 = Bu + (size_t)(bn + r0) * RR + gg0 * 8;
    const _Float16* pb1 = Bu + (size_t)(bn + r1) * RR + gg1 * 8;
    for (int k0 = 0; k0 < RR; k0 += BK) {
      gload_lds16(pa0 + k0, ldsA0);
      gload_lds16(pa1 + k0, ldsA1);
      gload_lds16(pb0 + k0, ldsB0);
      gload_lds16(pb1 + k0, ldsB1);
      __syncthreads();  // vmcnt drain + barrier: LDS tile ready
      f16x8 Af[4], Bf[4];
#pragma unroll
      for (int i = 0; i < 4; ++i) {
        int ra_ = wm + i * 16 + lm;
        int rb_ = wn + i * 16 + lm;
        Af[i] = *(const f16x8*)&As[ra_][(quad ^ ((ra_ >> 1) & 3)) * 8];
        Bf[i] = *(const f16x8*)&Bs[rb_][(quad ^ ((rb_ >> 1) & 3)) * 8];
      }
#pragma unroll
      for (int i = 0; i < 4; ++i)
#pragma unroll
        for (int j = 0; j < 4; ++j)
          accP[i][j] = __builtin_amdgcn_mfma_f32_16x16x32_f16(Af[i], Bf[j], accP[i][j], 0, 0, 0);
      __syncthreads();  // all reads done before next overwrite
    }
  }

  // ---- pass 2: S over DD (24 k-steps) ----
  f32x4 accS[4][4];
#pragma unroll
  for (int i = 0; i < 4; ++i)
#pragma unroll
    for (int j = 0; j < 4; ++j) accS[i][j] = (f32x4){0.f, 0.f, 0.f, 0.f};
  {
    const _Float16* pa0 = Aw + (size_t)(bm + r0) * DD + gg0 * 8;
    const _Float16* pa1 = Aw + (size_t)(bm + r1) * DD + gg1 * 8;
    const _Float16* pb0 = Bw + (size_t)(bn + r0) * DD + gg0 * 8;
    const _Float16* pb1 = Bw + (size_t)(bn + r1) * DD + gg1 * 8;
    for (int k0 = 0; k0 < DD; k0 += BK) {
      gload_lds16(pa0 + k0, ldsA0);
      gload_lds16(pa1 + k0, ldsA1);
      gload_lds16(pb0 + k0, ldsB0);
      gload_lds16(pb1 + k0, ldsB1);
      __syncthreads();
      f16x8 Af[4], Bf[4];
#pragma unroll
      for (int i = 0; i < 4; ++i) {
        int ra_ = wm + i * 16 + lm;
        int rb_ = wn + i * 16 + lm;
        Af[i] = *(const f16x8*)&As[ra_][(quad ^ ((ra_ >> 1) & 3)) * 8];
        Bf[i] = *(const f16x8*)&Bs[rb_][(quad ^ ((rb_ >> 1) & 3)) * 8];
      }
#pragma unroll
      for (int i = 0; i < 4; ++i)
#pragma unroll
        for (int j = 0; j < 4; ++j)
          accS[i][j] = __builtin_amdgcn_mfma_f32_16x16x32_f16(Af[i], Bf[j], accS[i][j], 0, 0, 0);
      __syncthreads();
    }
  }

  // ---- epilogue ----
  float scale = fminf(expf(p_log_scale[0]), 20.f);
  float qs = L2E / get_eps(p_log_eps);  // mh -> q units
#pragma unroll
  for (int i = 0; i < 4; ++i)
#pragma unroll
    for (int j = 0; j < 4; ++j) {
      int col = bn + wn + j * 16 + lm;
      if (col >= N) continue;
      float BB = BBv[col];
#pragma unroll
      for (int r = 0; r < 4; ++r) {
        int row = bm + wm + i * 16 + quad * 4 + r;  // < 512 always
        float S = accS[i][j][r];
        float mh = fmaxf(AAv[row] + BB - 2.f * (S + accP[i][j][r]), 0.f);
        Sd[(size_t)row * N + col] = fmaf(scale, S, tbias[row]);
        mhq[(size_t)row * VP + col] = (_Float16)(mh * qs);
      }
    }
}

// ---------------------------------------------------------------------------
// P-GEMM (aU16 @ wU16^T, Kd=192) + fused epilogue (tight-workspace fallback):
//   Sd <- scale*S + bias ;  mhq <- fp16( relu(AA+BB-2(S+P)) * L2E/eps )
// ---------------------------------------------------------------------------
__global__ __launch_bounds__(256, 2)
void gemm16_p(const _Float16* __restrict__ A, const _Float16* __restrict__ B,
              float* __restrict__ Sd, _Float16* __restrict__ mhq,
              const float* __restrict__ AAv, const float* __restrict__ BBv,
              const float* __restrict__ tbias,
              const float* __restrict__ p_log_scale,
              const float* __restrict__ p_log_eps, int M, int N, int Kd) {
  __shared__ _Float16 As[BM][LDK];
  __shared__ _Float16 Bs[BN][LDK];
  const int tid = threadIdx.x;
  const int bm = blockIdx.y * BM;
  const int bn = blockIdx.x * BN;
  const int srow = tid >> 1;
  const int skb = (tid & 1) << 4;
  const int wave = tid >> 6;
  const int lane = tid & 63;
  const int wm = (wave >> 1) << 6;
  const int wn = (wave & 1) << 6;
  const int lm = lane & 15;
  const int quad = lane >> 4;
  f32x4 acc[4][4];
#pragma unroll
  for (int i = 0; i < 4; ++i)
#pragma unroll
    for (int j = 0; j < 4; ++j) acc[i][j] = (f32x4){0.f, 0.f, 0.f, 0.f};
  const int ra = bm + srow;
  const int rb = bn + srow;
  for (int k0 = 0; k0 < Kd; k0 += BK) {
    f16x8 a0 = (f16x8)(_Float16)0, a1 = a0, b0 = a0, b1 = a0;
    if (ra < M) {
      const f16x8* p = (const f16x8*)(A + (size_t)ra * Kd + k0 + skb);
      a0 = p[0]; a1 = p[1];
    }
    if (rb < N) {
      const f16x8* p = (const f16x8*)(B + (size_t)rb * Kd + k0 + skb);
      b0 = p[0]; b1 = p[1];
    }
    __syncthreads();
    *(f16x8*)&As[srow][skb] = a0; *(f16x8*)&As[srow][skb + 8] = a1;
    *(f16x8*)&Bs[srow][skb] = b0; *(f16x8*)&Bs[srow][skb + 8] = b1;
    __syncthreads();
    f16x8 Af[4], Bf[4];
#pragma unroll
    for (int i = 0; i < 4; ++i) {
      Af[i] = *(const f16x8*)&As[wm + i * 16 + lm][quad * 8];
      Bf[i] = *(const f16x8*)&Bs[wn + i * 16 + lm][quad * 8];
    }
#pragma unroll
    for (int i = 0; i < 4; ++i)
#pragma unroll
      for (int j = 0; j < 4; ++j)
        acc[i][j] = __builtin_amdgcn_mfma_f32_16x16x32_f16(Af[i], Bf[j], acc[i][j], 0, 0, 0);
  }
  float scale = fminf(expf(p_log_scale[0]), 20.f);
  float qs = L2E / get_eps(p_log_eps);  // mh -> q units
#pragma unroll
  for (int i = 0; i < 4; ++i)
#pragma unroll
    for (int j = 0; j < 4; ++j) {
      int col = bn + wn + j * 16 + lm;
      if (col >= N) continue;
      float BB = BBv[col];
#pragma unroll
      for (int r = 0; r < 4; ++r) {
        int row = bm + wm + i * 16 + quad * 4 + r;  // < 512 always
        size_t idx = (size_t)row * N + col;
        float S = Sd[idx];
        float mh = fmaxf(AAv[row] + BB - 2.f * (S + acc[i][j][r]), 0.f);
        Sd[idx] = fmaf(scale, S, tbias[row]);
        mhq[(size_t)row * VP + col] = (_Float16)(mh * qs);
      }
    }
}

// ---------------------------------------------------------------------------
// out[r] = 1 + sum(X16[r,:]^2), cols <= 256
// ---------------------------------------------------------------------------
__global__ __launch_bounds__(256)
void row_sumsq16(const _Float16* __restrict__ X, float* __restrict__ out, int cols) {
  int r = blockIdx.x;
  int t = threadIdx.x;
  float x = (t < cols) ? (float)X[(size_t)r * cols + t] : 0.f;
  __shared__ float red[256];
  red[t] = x * x;
  __syncthreads();
  for (int off = 128; off > 0; off >>= 1) {
    if (t < off) red[t] += red[t + off];
    __syncthreads();
  }
  if (t == 0) out[r] = 1.0f + red[0];
}

// ---------------------------------------------------------------------------
// Sinkhorn row (log2 domain): lu2[k] = -(Mv2 + log2(sum_v 2^(lv2[v]-Mv2-q)))
// ---------------------------------------------------------------------------
__global__ __launch_bounds__(1024)
void sink_row(const _Float16* __restrict__ mhq, const float* __restrict__ lv2,
              float* __restrict__ lu2,
              const unsigned* __restrict__ Mv_slot, unsigned* __restrict__ Mu_slot) {
  int k = blockIdx.x;
  int t = threadIdx.x;
  float Mv2 = dec_f(*Mv_slot);
  const _Float16* row = mhq + (size_t)k * VP;
  float s[8] = {0.f, 0.f, 0.f, 0.f, 0.f, 0.f, 0.f, 0.f};
#pragma unroll
  for (int j = 0; j < 6; ++j) {
    int v = j * 8192 + t * 8;
    f16x8 hv = *(const f16x8*)(row + v);
    float4 l0 = *(const float4*)(lv2 + v);
    float4 l1 = *(const float4*)(lv2 + v + 4);
    float lv[8] = {l0.x, l0.y, l0.z, l0.w, l1.x, l1.y, l1.z, l1.w};
#pragma unroll
    for (int i = 0; i < 8; ++i)
      s[i] += fast_exp2(lv[i] - Mv2 - (float)hv[i]);
  }
  {
    int v = 49152 + t;
    s[0] += fast_exp2(lv2[v] - Mv2 - (float)row[v]);
    v = 50176 + t;
    if (v < VV) s[1] += fast_exp2(lv2[v] - Mv2 - (float)row[v]);
  }
  float sum = ((s[0] + s[1]) + (s[2] + s[3])) + ((s[4] + s[5]) + (s[6] + s[7]));
  __shared__ float red[1024];
  red[t] = sum;
  __syncthreads();
  for (int off = 512; off > 0; off >>= 1) {
    if (t < off) red[t] += red[t + off];
    __syncthreads();
  }
  if (t == 0) {
    float lu = -(Mv2 + log2f(red[0]));
    lu2[k] = lu;
    atomicMax(Mu_slot, enc_f(lu));
  }
}

// ---------------------------------------------------------------------------
// Sinkhorn col: lv2[v] = -(Mu2 + log2(sum_k 2^(lu2[k]-Mu2-q)))
// ---------------------------------------------------------------------------
__global__ __launch_bounds__(256)
void sink_col(const _Float16* __restrict__ mhq, const float* __restrict__ lu2,
              float* __restrict__ lv2,
              const unsigned* __restrict__ Mu_slot, unsigned* __restrict__ Mv_next) {
  __shared__ float lu_s[KK];
  int t = threadIdx.x;
  for (int i = t; i < KK; i += 256) lu_s[i] = lu2[i];
  __syncthreads();
  float Mu2 = dec_f(*Mu_slot);
  int cp = blockIdx.x * 64 + (t & 63);
  int v0 = cp * 2;
  int kc = t >> 6;
  float sA = 0.f, sB = 0.f;
  if (v0 < VV) {
    const _Float16* base = mhq + v0;
#pragma unroll 4
    for (int k = kc * 128; k < kc * 128 + 128; ++k) {
      f16x2 hv = *(const f16x2*)(base + (size_t)k * VP);
      float lu = lu_s[k] - Mu2;
      sA += fast_exp2(lu - (float)hv[0]);
      sB += fast_exp2(lu - (float)hv[1]);
    }
  }
  __shared__ float pA[256], pB[256];
  __shared__ unsigned em[64];
  pA[t] = sA; pB[t] = sB;
  __syncthreads();
  if (t < 64) {
    unsigned e = ENC_NEG_INF;
    if (v0 < VV) {
      float a = (pA[t] + pA[t + 64]) + (pA[t + 128] + pA[t + 192]);
      float lv = -(Mu2 + log2f(a));
      lv2[v0] = lv;
      e = enc_f(lv);
      if (v0 + 1 < VV) {
        float b = (pB[t] + pB[t + 64]) + (pB[t + 128] + pB[t + 192]);
        float lv1 = -(Mu2 + log2f(b));
        lv2[v0 + 1] = lv1;
        unsigned e1 = enc_f(lv1);
        if (e1 > e) e = e1;
      }
    }
    em[t] = e;
  }
  __syncthreads();
  for (int off = 32; off > 0; off >>= 1) {
    if (t < off && em[t + off] > em[t]) em[t] = em[t + off];
    __syncthreads();
  }
  if (t == 0) atomicMax(Mv_next, em[0]);
}

// ---------------------------------------------------------------------------
// final pass 1: row_s[k] = sum_v exp(logit - 30)   (logits clipped at +-30)
//  logit x = d - c2*q + c3*(lu2+lv2);  c2=(LAM*eps+GAM)/L2E, c3=GAM/L2E
// ---------------------------------------------------------------------------
__global__ __launch_bounds__(1024)
void final_sum(const float* __restrict__ direct, const _Float16* __restrict__ mhq,
               const float* __restrict__ lu2, const float* __restrict__ lv2,
               float* __restrict__ row_s, const float* __restrict__ p_log_eps) {
  int k = blockIdx.x;
  int t = threadIdx.x;
  float eps = get_eps(p_log_eps);
  float c2 = (LAM * eps + GAM) / L2E;
  float c3 = GAM / L2E;
  float base_lu = c3 * lu2[k];
  const float* drow = direct + (size_t)k * VV;
  const _Float16* mrow = mhq + (size_t)k * VP;
  float s[8] = {0.f, 0.f, 0.f, 0.f, 0.f, 0.f, 0.f, 0.f};
#pragma unroll
  for (int j = 0; j < 6; ++j) {
    int v = j * 8192 + t * 8;
    f16x8 hv = *(const f16x8*)(mrow + v);
    float4 d0 = *(const float4*)(drow + v);
    float4 d1 = *(const float4*)(drow + v + 4);
    float4 l0 = *(const float4*)(lv2 + v);
    float4 l1 = *(const float4*)(lv2 + v + 4);
    float dd[8] = {d0.x, d0.y, d0.z, d0.w, d1.x, d1.y, d1.z, d1.w};
    float lv[8] = {l0.x, l0.y, l0.z, l0.w, l1.x, l1.y, l1.z, l1.w};
#pragma unroll
    for (int i = 0; i < 8; ++i) {
      float x = fmaf(-c2, (float)hv[i], fmaf(c3, lv[i], dd[i] + base_lu));
      x = fminf(30.f, fmaxf(-30.f, x));
      s[i] += fast_exp2(fmaf(x, L2E, -30.f * L2E));
    }
  }
  {
    int v = 49152 + t;
    float x = fmaf(-c2, (float)mrow[v], fmaf(c3, lv2[v], drow[v] + base_lu));
    x = fminf(30.f, fmaxf(-30.f, x));
    s[0] += fast_exp2(fmaf(x, L2E, -30.f * L2E));
    v = 50176 + t;
    if (v < VV) {
      x = fmaf(-c2, (float)mrow[v], fmaf(c3, lv2[v], drow[v] + base_lu));
      x = fminf(30.f, fmaxf(-30.f, x));
      s[1] += fast_exp2(fmaf(x, L2E, -30.f * L2E));
    }
  }
  float sum = ((s[0] + s[1]) + (s[2] + s[3])) + ((s[4] + s[5]) + (s[6] + s[7]));
  __shared__ float red[1024];
  red[t] = sum;
  __syncthreads();
  for (int off = 512; off > 0; off >>= 1) {
    if (t < off) red[t] += red[t + off];
    __syncthreads();
  }
  if (t == 0) row_s[k] = red[0];
}

// ---------------------------------------------------------------------------
// final pass 2: out[k,v] = exp(logit - 30) / row_s[k]
// ---------------------------------------------------------------------------
__global__ __launch_bounds__(256)
void final_write(float* __restrict__ out, const _Float16* __restrict__ mhq,
                 const float* __restrict__ lu2, const float* __restrict__ lv2,
                 const float* __restrict__ row_s, const float* __restrict__ p_log_eps) {
  int v = blockIdx.x * 256 + threadIdx.x;
  int k = blockIdx.y;
  if (v >= VV) return;
  float eps = get_eps(p_log_eps);
  float c2 = (LAM * eps + GAM) / L2E;
  float c3 = GAM / L2E;
  size_t idx = (size_t)k * VV + v;
  float x = fmaf(-c2, (float)mhq[(size_t)k * VP + v],
                 fmaf(c3, lv2[v], out[idx] + c3 * lu2[k]));
  x = fminf(30.f, fmaxf(-30.f, x));
  out[idx] = fast_exp2(fmaf(x, L2E, -30.f * L2E)) / row_s[k];
}

// ---------------------------------------------------------------------------
// launch
// ---------------------------------------------------------------------------
extern "C" void kernel_launch(void* const* d_in, const int* in_sizes, int n_in,
                              void* d_out, int out_size, void* d_ws, size_t ws_size,
                              hipStream_t stream) {
  (void)in_sizes; (void)n_in; (void)out_size;
  const float* WE        = (const float*)d_in[0];
  const float* anchors   = (const float*)d_in[1];
  const float* MU        = (const float*)d_in[2];
  const float* log_eps   = (const float*)d_in[3];
  const float* log_scale = (const float*)d_in[4];
  const float* tbias     = (const float*)d_in[5];
  const float* Wp        = (const float*)d_in[6];
  float* out = (float*)d_out;

  // workspace layout. If ws_size allows, give mhq its own region (required by
  // the fused S+P GEMM, which reads w16 while writing mhq). Otherwise fall
  // back to the alias layout (mhq over w16, dead-after-S) + two-kernel path.
  const size_t H_W16 = (size_t)VV * DD;   // 38,597,376 halfs
  const size_t H_MHQ = (size_t)KK * VP;   // 25,739,264 halfs
  const size_t H_WU  = (size_t)VV * RR;
  const size_t H_A16 = (size_t)KK * DD;
  const size_t H_AU  = (size_t)KK * RR;
  const size_t H_UT  = (size_t)RR * DD;
  const size_t FB_FLOATS = 102064 + 32;   // fp32 region incl. slots
  const size_t need_roomy =
      2 * (H_W16 + H_MHQ + H_WU + H_A16 + H_AU + H_UT) + 4 * FB_FLOATS;
  const bool roomy = ws_size >= need_roomy;

  _Float16* hb = (_Float16*)d_ws;
  _Float16* w16 = hb;
  size_t ho = H_W16;
  _Float16* mhq;
  if (roomy) { mhq = hb + ho; ho += H_MHQ; }
  else       { mhq = hb; }                 // alias w16 (dead after S GEMM)
  _Float16* wU16 = hb + ho; ho += H_WU;
  _Float16* a16  = hb + ho; ho += H_A16;
  _Float16* aU16 = hb + ho; ho += H_AU;
  _Float16* Ut16 = hb + ho; ho += H_UT;
  float* fb = (float*)(hb + ho);
  float* BBv   = fb;           // 50264
  float* AAv   = fb + 50264;   // 512
  float* lu2   = fb + 50776;   // 512
  float* lv2   = fb + 51288;   // 50264
  float* row_s = fb + 101552;  // 512
  unsigned* slots = (unsigned*)(fb + 102064);  // 25
  unsigned* Mv_slots = slots;
  unsigned* Mu_slots = slots + 12;
  unsigned* eye_flag = slots + 24;

  const int VB = (VV + 255) / 256;      // 197
  const int MB_V = (VV + BM - 1) / BM;  // 393

  prep<<<1286, 256, 0, stream>>>(MU, lv2, slots, anchors, Ut16, a16);
  check_eye<<<(DD * DD + 255) / 256, 256, 0, stream>>>(Wp, eye_flag);
  // fallback only (no-op when Wp == I): w16 = fp16(WE @ Wp^T)
  gemm_we_fallback<<<dim3(DD / BN, MB_V), 256, 0, stream>>>(WE, Wp, w16, VV, DD, DD, eye_flag);
  norm_w<<<VV, 256, 0, stream>>>(WE, w16, eye_flag);
  // wU16 = w16 @ Ut16^T ; aU16 = a16 @ Ut16^T
  gemm16<1><<<dim3(2, MB_V), 256, 0, stream>>>(w16, Ut16, wU16, VV, RR, DD);
  gemm16<1><<<dim3(2, 4), 256, 0, stream>>>(a16, Ut16, aU16, KK, RR, DD);
  row_sumsq16<<<VV, 256, 0, stream>>>(wU16, BBv, RR);
  row_sumsq16<<<KK, 256, 0, stream>>>(aU16, AAv, RR);
  if (roomy) {
    // fused S+P, global_load_lds staging, grid (bm, bn) for B-tile L3 reuse
    gemm_sp<<<dim3(4, MB_V), 256, 0, stream>>>(a16, w16, aU16, wU16, out, mhq,
                                               AAv, BBv, tbias, log_scale,
                                               log_eps, KK, VV);
  } else {
    // S = a16 @ w16^T -> out (fp32)
    gemm16<0><<<dim3(MB_V, 4), 256, 0, stream>>>(a16, w16, out, KK, VV, DD);
    // P GEMM + fused epilogue -> out = scale*S+bias, mhq = fp16(mh*L2E/eps)
    gemm16_p<<<dim3(MB_V, 4), 256, 0, stream>>>(aU16, wU16, out, mhq, AAv, BBv,
                                                tbias, log_scale, log_eps, KK, VV, RR);
  }
  for (int it = 0; it < 10; ++it) {
    sink_row<<<KK, 1024, 0, stream>>>(mhq, lv2, lu2, Mv_slots + it, Mu_slots + it);
    sink_col<<<MB_V, 256, 0, stream>>>(mhq, lu2, lv2, Mu_slots + it, Mv_slots + it + 1);
  }
  final_sum<<<KK, 1024, 0, stream>>>(out, mhq, lu2, lv2, row_s, log_eps);
  final_write<<<dim3(VB, KK), 256, 0, stream>>>(out, mhq, lu2, lv2, row_s, log_eps);
}